// Round 2
// baseline (311.521 us; speedup 1.0000x reference)
//
#include <hip/hip_runtime.h>
#include <cstdint>
#include <cstddef>

#define NNODES 50000
#define NEDGES 800000
#define INDIM  256
#define HD     128   // H*D
#define NH     4
#define NEG    0.2f

#define SCAN_B ((NNODES + 255) / 256)   // 196 blocks

// fusedA block partition
#define CONVH_BLKS (NNODES * INDIM / 8 / 256)       // 6250
#define HIST_BLKS  ((NEDGES + 255) / 256)           // 3125
#define CONVW_BLKS 64
// fusedB block partition
#define GEMM_BLKS  (2 * ((NNODES + 127) / 128))     // 782
#define SCAT_BLKS  ((NEDGES + 255) / 256)           // 3125

typedef __attribute__((ext_vector_type(8))) short   short8;   // 8 bf16 (4 VGPRs)
typedef __attribute__((ext_vector_type(8))) ushort  ushort8;
typedef __attribute__((ext_vector_type(4))) float   floatx4;

// f32 -> bf16 (round-to-nearest-even), raw bits
__device__ __forceinline__ ushort f2bf(float f) {
    unsigned u = __float_as_uint(f);
    unsigned r = u + 0x7fffu + ((u >> 16) & 1u);
    return (ushort)(r >> 16);
}
__device__ __forceinline__ float bf2f(ushort u) {
    return __uint_as_float(((unsigned)u) << 16);
}

// LDS chunk swizzle: conflict-free staging writes + fragment reads
__device__ __forceinline__ int swz(int c) { return c ^ ((c >> 4) & 7); }

// ================= fusedA: conv_h | hist | conv_w  (all independent) =================
__global__ __launch_bounds__(256) void fusedA_kernel(
        const float* __restrict__ h, ushort* __restrict__ h_bf,
        const int* __restrict__ dst, int* __restrict__ cnt_work,
        const float* __restrict__ Wsrc, const float* __restrict__ Wdst,
        ushort* __restrict__ Wt) {
    __shared__ float t[32][33];
    const int bid = blockIdx.x;
    const int tid = threadIdx.x;

    if (bid < CONVH_BLKS) {
        // ---- h convert: f32 -> bf16, 8 elems/thread ----
        int idx = bid * 256 + tid;                    // chunk of 8
        const int total = NNODES * INDIM / 8;         // 1.6M
        if (idx >= total) return;
        const float* p = h + (size_t)idx * 8;
        float4 v0 = *(const float4*)p;
        float4 v1 = *(const float4*)(p + 4);
        ushort8 o;
        o[0] = f2bf(v0.x); o[1] = f2bf(v0.y); o[2] = f2bf(v0.z); o[3] = f2bf(v0.w);
        o[4] = f2bf(v1.x); o[5] = f2bf(v1.y); o[6] = f2bf(v1.z); o[7] = f2bf(v1.w);
        *(ushort8*)(h_bf + (size_t)idx * 8) = o;
    } else if (bid < CONVH_BLKS + HIST_BLKS) {
        // ---- histogram of dst ----
        int e = (bid - CONVH_BLKS) * 256 + tid;
        if (e < NEDGES) atomicAdd(cnt_work + dst[e], 1);
    } else {
        // ---- W convert+transpose (LDS-tiled): Wt[n][k] bf16 ----
        int wb = bid - (CONVH_BLKS + HIST_BLKS);      // 0..63
        int kb = (wb & 7) * 32, nb = (wb >> 3) * 32;
        int tx = tid & 31, ty = tid >> 5;
        for (int i = ty; i < 32; i += 8) {
            int k = kb + i, n = nb + tx;
            float v = (n < HD) ? Wsrc[(size_t)k * HD + n] : Wdst[(size_t)k * HD + (n - HD)];
            t[i][tx] = v;
        }
        __syncthreads();
        for (int i = ty; i < 32; i += 8) {
            int n = nb + i, k = kb + tx;
            Wt[(size_t)n * INDIM + k] = f2bf(t[tx][i]);
        }
    }
}

// ================= CSR scans (unchanged) =================
__global__ __launch_bounds__(256) void scan_partial_kernel(
        const int* __restrict__ cnt, int* __restrict__ partials) {
    __shared__ int lds[256];
    int i = blockIdx.x * 256 + threadIdx.x;
    lds[threadIdx.x] = (i < NNODES) ? cnt[i] : 0;
    __syncthreads();
    for (int off = 128; off > 0; off >>= 1) {
        if (threadIdx.x < off) lds[threadIdx.x] += lds[threadIdx.x + off];
        __syncthreads();
    }
    if (threadIdx.x == 0) partials[blockIdx.x] = lds[0];
}

__global__ __launch_bounds__(256) void scan_offsets_kernel(
        int* __restrict__ partials, int* __restrict__ rowptr) {
    __shared__ int lds[256];
    int t = threadIdx.x;
    int v = (t < SCAN_B) ? partials[t] : 0;
    lds[t] = v;
    __syncthreads();
    for (int off = 1; off < 256; off <<= 1) {
        int u = (t >= off) ? lds[t - off] : 0;
        __syncthreads();
        lds[t] += u;
        __syncthreads();
    }
    if (t < SCAN_B) partials[t] = lds[t] - v;      // exclusive
    if (t == 255) rowptr[NNODES] = lds[255];       // total
}

__global__ __launch_bounds__(256) void scan_final_kernel(
        int* __restrict__ cnt_work, const int* __restrict__ partials,
        int* __restrict__ rowptr) {
    __shared__ int lds[256];
    int i = blockIdx.x * 256 + threadIdx.x;
    int t = threadIdx.x;
    int v = (i < NNODES) ? cnt_work[i] : 0;
    lds[t] = v;
    __syncthreads();
    for (int off = 1; off < 256; off <<= 1) {
        int u = (t >= off) ? lds[t - off] : 0;
        __syncthreads();
        lds[t] += u;
        __syncthreads();
    }
    if (i < NNODES) {
        int start = partials[blockIdx.x] + lds[t] - v;
        rowptr[i] = start;
        cnt_work[i] = start;
    }
}

// ================= fusedB: MFMA GEMM | scatter  (both ready after scans+fusedA) =====
__global__ __launch_bounds__(256) void fusedB_kernel(
        const ushort* __restrict__ h_bf, const ushort* __restrict__ Wt,
        const float* __restrict__ bsrc, const float* __restrict__ bdst,
        ushort* __restrict__ el_bf, float* __restrict__ er,
        const int* __restrict__ src, const int* __restrict__ dst,
        int* __restrict__ cnt_work, int2* __restrict__ epair) {
    __shared__ ushort As[512 * 8];  // 512 fragment-chunks of 8 bf16
    __shared__ ushort Bs[512 * 8];

    const int bid = blockIdx.x;
    const int tid = threadIdx.x;

    if (bid >= GEMM_BLKS) {
        // ---- scatter: build CSR edge list (packed {eidx, esrc} 8B store) ----
        int e = (bid - GEMM_BLKS) * 256 + tid;
        if (e >= NEDGES) return;
        int s = src[e];
        int pos = atomicAdd(cnt_work + dst[e], 1);
        epair[pos] = make_int2(e, s);
        return;
    }

    // ---- GEMM: bx==0 -> el (bf16 out), bx==1 -> er (f32 out). 128x128 per block ----
    const int bx = bid & 1, by = bid >> 1;
    const int wave = tid >> 6, lane = tid & 63;
    const int row0 = by * 128;
    const int col0 = bx * 128;   // 0 -> el, 128 -> er
    const int l15  = lane & 15, quad = lane >> 4;

    floatx4 acc[2][8];
#pragma unroll
    for (int i = 0; i < 2; ++i)
#pragma unroll
        for (int j = 0; j < 8; ++j) acc[i][j] = (floatx4){0.f, 0.f, 0.f, 0.f};

    for (int kk = 0; kk < INDIM; kk += 32) {
#pragma unroll
        for (int it = 0; it < 2; ++it) {
            int idx = tid + it * 256;    // 0..511
            int r = idx >> 2;            // 0..127
            int kq = idx & 3;            // k-quad (8 elems)
            int c = (r >> 4) * 64 + kq * 16 + (r & 15);
            // ---- A: pre-converted bf16 ----
            int grow = row0 + r;
            ushort8 aw = (ushort8){0,0,0,0,0,0,0,0};
            if (grow < NNODES)
                aw = *(const ushort8*)(h_bf + (size_t)grow * INDIM + kk + kq * 8);
            *(ushort8*)(As + swz(c) * 8) = aw;
            // ---- B ----
            ushort8 bw = *(const ushort8*)(Wt + (size_t)(col0 + r) * INDIM + kk + kq * 8);
            *(ushort8*)(Bs + swz(c) * 8) = bw;
        }
        __syncthreads();

        short8 af[2], bf[8];
#pragma unroll
        for (int tm = 0; tm < 2; ++tm) {
            int c = (wave * 2 + tm) * 64 + quad * 16 + l15;
            af[tm] = *(const short8*)(As + swz(c) * 8);
        }
#pragma unroll
        for (int tn = 0; tn < 8; ++tn) {
            int c = tn * 64 + quad * 16 + l15;
            bf[tn] = *(const short8*)(Bs + swz(c) * 8);
        }
#pragma unroll
        for (int tm = 0; tm < 2; ++tm)
#pragma unroll
            for (int tn = 0; tn < 8; ++tn)
                acc[tm][tn] = __builtin_amdgcn_mfma_f32_16x16x32_bf16(
                    af[tm], bf[tn], acc[tm][tn], 0, 0, 0);
        __syncthreads();
    }

    // epilogue: C/D layout col=lane&15, row=quad*4+reg
    if (col0 == 0) {
#pragma unroll
        for (int tn = 0; tn < 8; ++tn) {
            int col = tn * 16 + l15;
            float bias = bsrc[col];
#pragma unroll
            for (int tm = 0; tm < 2; ++tm)
#pragma unroll
                for (int reg = 0; reg < 4; ++reg) {
                    int row = row0 + wave * 32 + tm * 16 + quad * 4 + reg;
                    if (row < NNODES)
                        el_bf[(size_t)row * HD + col] = f2bf(acc[tm][tn][reg] + bias);
                }
        }
    } else {
#pragma unroll
        for (int tn = 0; tn < 8; ++tn) {
            int col = tn * 16 + l15;
            float bias = bdst[col];
#pragma unroll
            for (int tm = 0; tm < 2; ++tm)
#pragma unroll
                for (int reg = 0; reg < 4; ++reg) {
                    int row = row0 + wave * 32 + tm * 16 + quad * 4 + reg;
                    if (row < NNODES)
                        er[(size_t)row * HD + col] = acc[tm][tn][reg] + bias;
                }
        }
    }
}

// ================= node_fused: transposed edge-per-lane layout =================
// lane = (head hh = lane>>4, half = (lane>>3)&1, j8 = lane&7).
// Each lane owns 16 dims (dbase = (lane>>3)*16) and processes edges j8, j8+8, ...
// Per 8-edge chunk: dot in-lane + 1 pair-shfl; chunk-level online softmax
// (1 rescale / 8 edges); aggregation via in-register fma (el reused, no re-gather).
// Final: reduce-scatter acc[16] across the 8 j-lanes -> float2/lane output.
#define DEGCAP 128

__global__ __launch_bounds__(256) void node_fused_kernel(
        const ushort* __restrict__ el_bf, const float* __restrict__ er,
        const int* __restrict__ rowptr, const int2* __restrict__ epair,
        const float* __restrict__ attn,
        float* __restrict__ out_feat, float* __restrict__ out_a) {
    __shared__ float sp[4][DEGCAP * NH];   // 2 KB per wave

    const int wv = threadIdx.x >> 6;
    const int n = blockIdx.x * 4 + wv;
    if (n >= NNODES) return;
    const int lane = threadIdx.x & 63;
    const int hh   = lane >> 4;
    const int j8   = lane & 7;
    const int dbase = (lane >> 3) * 16;    // hh*32 + half*16
    const int lo = rowptr[n], hi = rowptr[n + 1];
    const int deg = hi - lo;
    float* spw = sp[wv];

    if (deg == 0) {
        int o = (j8 & 1) * 8 + ((j8 >> 1) & 1) * 4 + ((j8 >> 2) & 1) * 2;
        *(float2*)(out_feat + (size_t)n * HD + dbase + o) = make_float2(0.f, 0.f);
        return;
    }

    if (deg <= DEGCAP) {
        float erv[16], av[16], acc[16];
        {
            const float4* p4 = (const float4*)(er + (size_t)n * HD + dbase);
            const float4* a4 = (const float4*)(attn + dbase);
#pragma unroll
            for (int q = 0; q < 4; ++q) {
                float4 t = p4[q];
                erv[4*q] = t.x; erv[4*q+1] = t.y; erv[4*q+2] = t.z; erv[4*q+3] = t.w;
                float4 u = a4[q];
                av[4*q] = u.x; av[4*q+1] = u.y; av[4*q+2] = u.z; av[4*q+3] = u.w;
            }
        }
#pragma unroll
        for (int d = 0; d < 16; ++d) acc[d] = 0.f;
        float m = -3.4e38f, lsum = 0.f;

        // software pipeline: indices 2-deep, el 1-deep
        int t0 = (j8 < deg) ? j8 : (deg - 1);
        int s_cur = epair[lo + t0].y;
        uint4 el_lo, el_hi;
        {
            const ushort* ep = el_bf + (size_t)s_cur * HD + dbase;
            el_lo = *(const uint4*)ep;
            el_hi = *(const uint4*)(ep + 8);
        }
        int s_nxt = s_cur;
        if (deg > 8) {
            int t = 8 + j8; if (t >= deg) t = deg - 1;
            s_nxt = epair[lo + t].y;
        }

        for (int base = 0; base < deg; base += 8) {
            // prefetch next chunk's el (its index was loaded last iteration)
            uint4 nl_lo = el_lo, nl_hi = el_hi;
            if (base + 8 < deg) {
                const ushort* ep = el_bf + (size_t)s_nxt * HD + dbase;
                nl_lo = *(const uint4*)ep;
                nl_hi = *(const uint4*)(ep + 8);
            }
            int s_n2 = s_nxt;
            if (base + 16 < deg) {
                int t = base + 16 + j8; if (t >= deg) t = deg - 1;
                s_n2 = epair[lo + t].y;
            }

            // unpack el -> f32 (bit ops only)
            float ev[16];
            {
                const unsigned* wl = (const unsigned*)&el_lo;
                const unsigned* wh = (const unsigned*)&el_hi;
#pragma unroll
                for (int q = 0; q < 4; ++q) {
                    ev[2*q]       = __uint_as_float(wl[q] << 16);
                    ev[2*q + 1]   = __uint_as_float(wl[q] & 0xffff0000u);
                    ev[8 + 2*q]   = __uint_as_float(wh[q] << 16);
                    ev[8 + 2*q+1] = __uint_as_float(wh[q] & 0xffff0000u);
                }
            }
            // in-lane dot (2 fma chains for ILP); leaky = max(x, 0.2x)
            float pa = 0.f, pb = 0.f;
#pragma unroll
            for (int d = 0; d < 16; d += 2) {
                float x0 = ev[d]   + erv[d];   x0 = fmaxf(x0, NEG * x0);
                float x1 = ev[d+1] + erv[d+1]; x1 = fmaxf(x1, NEG * x1);
                pa = fmaf(x0, av[d],   pa);
                pb = fmaf(x1, av[d+1], pb);
            }
            float part = pa + pb;
            float p = part + __shfl_xor(part, 8, 64);   // combine the two halves
            bool valid = (base + j8) < deg;
            if (!valid) p = -3.4e38f;
            if (valid && (lane & 8) == 0) spw[(base + j8) * NH + hh] = p;

            // chunk max across the 8 j-lanes
            float cm = p;
            cm = fmaxf(cm, __shfl_xor(cm, 1, 64));
            cm = fmaxf(cm, __shfl_xor(cm, 2, 64));
            cm = fmaxf(cm, __shfl_xor(cm, 4, 64));
            float mn = fmaxf(m, cm);
            float sc = __expf(m - mn);     // one rescale per chunk
            float w  = __expf(p - mn);     // invalid lanes -> exp(-huge) = 0
            float ws = w;
            ws += __shfl_xor(ws, 1, 64);
            ws += __shfl_xor(ws, 2, 64);
            ws += __shfl_xor(ws, 4, 64);
            lsum = lsum * sc + ws;
#pragma unroll
            for (int d = 0; d < 16; ++d)
                acc[d] = fmaf(w, ev[d], acc[d] * sc);
            m = mn;
            el_lo = nl_lo; el_hi = nl_hi; s_nxt = s_n2;
        }

        float inv = 1.0f / lsum;

        // reduce-scatter acc[16] across the 8 j-lanes -> 2 dims per lane
#pragma unroll
        for (int k = 0; k < 8; ++k) {
            float send = (j8 & 1) ? acc[k] : acc[k + 8];
            float recv = __shfl_xor(send, 1, 64);
            float keep = (j8 & 1) ? acc[k + 8] : acc[k];
            acc[k] = keep + recv;
        }
#pragma unroll
        for (int k = 0; k < 4; ++k) {
            float send = (j8 & 2) ? acc[k] : acc[k + 4];
            float recv = __shfl_xor(send, 2, 64);
            float keep = (j8 & 2) ? acc[k + 4] : acc[k];
            acc[k] = keep + recv;
        }
#pragma unroll
        for (int k = 0; k < 2; ++k) {
            float send = (j8 & 4) ? acc[k] : acc[k + 2];
            float recv = __shfl_xor(send, 4, 64);
            float keep = (j8 & 4) ? acc[k + 2] : acc[k];
            acc[k] = keep + recv;
        }
        int o = (j8 & 1) * 8 + ((j8 >> 1) & 1) * 4 + ((j8 >> 2) & 1) * 2;
        *(float2*)(out_feat + (size_t)n * HD + dbase + o) =
            make_float2(acc[0] * inv, acc[1] * inv);

        // normalize + write attention weights (m, inv uniform per 16-lane head group)
        float mh   = __shfl(m,   (lane & 3) << 4, 64);
        float invh = __shfl(inv, (lane & 3) << 4, 64);
        for (int q = lane >> 2; q < deg; q += 16) {
            int e = epair[lo + q].x;
            float pq = spw[q * NH + (lane & 3)];
            out_a[(size_t)e * NH + (lane & 3)] = __expf(pq - mh) * invh;
        }
        return;
    }

    // ---- deg > DEGCAP fallback: old 2-dims-per-lane layout, 2-pass ----
    {
        const int l2 = lane * 2;
        const float2 rv = *(const float2*)(er + (size_t)n * HD + l2);
        const float a0 = attn[l2], a1 = attn[l2 + 1];
        float m = -3.4e38f, lsum = 0.f, acc0 = 0.f, acc1 = 0.f;
        ushort2 u;
        { int s_ = epair[lo].y; u = *(const ushort2*)(el_bf + (size_t)s_ * HD + l2); }
        for (int i = lo; i < hi; ++i) {
            float evx = bf2f(u.x), evy = bf2f(u.y);
            if (i + 1 < hi) { int s_ = epair[i + 1].y;
                u = *(const ushort2*)(el_bf + (size_t)s_ * HD + l2); }
            float x0 = evx + rv.x; x0 = fmaxf(x0, NEG * x0);
            float x1 = evy + rv.y; x1 = fmaxf(x1, NEG * x1);
            float p = x0 * a0 + x1 * a1;
            p += __shfl_xor(p, 1, 16);
            p += __shfl_xor(p, 2, 16);
            p += __shfl_xor(p, 4, 16);
            p += __shfl_xor(p, 8, 16);
            float mn = fmaxf(m, p);
            float sc = __expf(m - mn);
            float w  = __expf(p - mn);
            lsum = lsum * sc + w;
            acc0 = acc0 * sc + w * evx;
            acc1 = acc1 * sc + w * evy;
            m = mn;
        }
        float inv = 1.0f / lsum;
        *(float2*)(out_feat + (size_t)n * HD + l2) = make_float2(acc0 * inv, acc1 * inv);
        for (int i = lo; i < hi; ++i) {
            int s_ = epair[i].y;
            ushort2 uu = *(const ushort2*)(el_bf + (size_t)s_ * HD + l2);
            float evx = bf2f(uu.x), evy = bf2f(uu.y);
            float x0 = evx + rv.x; x0 = fmaxf(x0, NEG * x0);
            float x1 = evy + rv.y; x1 = fmaxf(x1, NEG * x1);
            float p = x0 * a0 + x1 * a1;
            p += __shfl_xor(p, 1, 16);
            p += __shfl_xor(p, 2, 16);
            p += __shfl_xor(p, 4, 16);
            p += __shfl_xor(p, 8, 16);
            if ((lane & 15) == 0) {
                int e = epair[i].x;
                out_a[(size_t)e * NH + hh] = __expf(p - m) * inv;
            }
        }
    }
}

extern "C" void kernel_launch(void* const* d_in, const int* in_sizes, int n_in,
                              void* d_out, int out_size, void* d_ws, size_t ws_size,
                              hipStream_t stream) {
    const float* h    = (const float*)d_in[0];
    const int*   src  = (const int*)d_in[1];
    const int*   dst  = (const int*)d_in[2];
    const float* Wsrc = (const float*)d_in[3];
    const float* bsrc = (const float*)d_in[4];
    const float* Wdst = (const float*)d_in[5];
    const float* bdst = (const float*)d_in[6];
    const float* attn = (const float*)d_in[7];

    float* out_feat = (float*)d_out;                       // N*128
    float* out_a    = out_feat + (size_t)NNODES * HD;      // E*4

    // h_bf scratch lives in d_out (38.4 MB region, fully rewritten later):
    // fusedA -> fusedB consume it before node_fused overwrites the region.
    ushort* h_bf = (ushort*)d_out;                         // N*256 bf16 = 25.6 MB

    // workspace layout (16B-aligned chunks)
    float*  er       = (float*)d_ws;                         // N*128 f32
    ushort* Wt       = (ushort*)(er + (size_t)NNODES * HD);  // 256*256 bf16
    ushort* el_bf    = Wt + 2 * HD * INDIM;                  // N*128 bf16
    int*    cnt_work = (int*)(el_bf + (size_t)NNODES * HD);  // N
    int2*   epair    = (int2*)(cnt_work + NNODES);           // E  {eidx, esrc}
    int*    rowptr   = (int*)(epair + NEDGES);               // N+1
    int*    partials = rowptr + NNODES + 1;                  // SCAN_B

    hipMemsetAsync(cnt_work, 0, NNODES * sizeof(int), stream);

    // fusedA: h->bf16 convert | dst histogram | W convert+transpose (independent)
    fusedA_kernel<<<CONVH_BLKS + HIST_BLKS + CONVW_BLKS, 256, 0, stream>>>(
        h, h_bf, dst, cnt_work, Wsrc, Wdst, Wt);

    // CSR prefix-sum chain
    scan_partial_kernel<<<SCAN_B, 256, 0, stream>>>(cnt_work, partials);
    scan_offsets_kernel<<<1, 256, 0, stream>>>(partials, rowptr);
    scan_final_kernel<<<SCAN_B, 256, 0, stream>>>(cnt_work, partials, rowptr);

    // fusedB: MFMA GEMM (el, er) | CSR scatter (independent at this point)
    fusedB_kernel<<<GEMM_BLKS + SCAT_BLKS, 256, 0, stream>>>(
        h_bf, Wt, bsrc, bdst, el_bf, er, src, dst, cnt_work, epair);

    node_fused_kernel<<<(NNODES + 3) / 4, 256, 0, stream>>>(
        el_bf, er, rowptr, epair, attn, out_feat, out_a);
}

// Round 4
// 305.186 us; speedup vs baseline: 1.0208x; 1.0208x over previous
//
#include <hip/hip_runtime.h>
#include <cstdint>
#include <cstddef>

#define NNODES 50000
#define NEDGES 800000
#define INDIM  256
#define HD     128   // H*D
#define NH     4
#define NEG    0.2f

#define SCAN_B ((NNODES + 255) / 256)   // 196 blocks

// fusedA block partition (hist | conv_w)
#define HIST_BLKS  ((NEDGES + 255) / 256)           // 3125
#define CONVW_BLKS 64
// fusedB block partition (gemm 128x256 | scatter)
#define GEMM_BLKS  ((NNODES + 127) / 128)           // 391
#define SCAT_BLKS  ((NEDGES + 255) / 256)           // 3125

typedef __attribute__((ext_vector_type(8))) short   short8;   // 8 bf16 (4 VGPRs)
typedef __attribute__((ext_vector_type(8))) ushort  ushort8;
typedef __attribute__((ext_vector_type(4))) float   floatx4;

// f32 -> bf16 (round-to-nearest-even), raw bits
__device__ __forceinline__ ushort f2bf(float f) {
    unsigned u = __float_as_uint(f);
    unsigned r = u + 0x7fffu + ((u >> 16) & 1u);
    return (ushort)(r >> 16);
}
__device__ __forceinline__ float bf2f(ushort u) {
    return __uint_as_float(((unsigned)u) << 16);
}

// LDS chunk swizzle: conflict-free staging writes + fragment reads
__device__ __forceinline__ int swz(int c) { return c ^ ((c >> 4) & 7); }

// ================= fusedA: hist | conv_w  (independent) =================
__global__ __launch_bounds__(256) void fusedA_kernel(
        const int* __restrict__ dst, int* __restrict__ cnt_work,
        const float* __restrict__ Wsrc, const float* __restrict__ Wdst,
        ushort* __restrict__ Wt) {
    __shared__ float t[32][33];
    const int bid = blockIdx.x;
    const int tid = threadIdx.x;

    if (bid < HIST_BLKS) {
        // ---- histogram of dst ----
        int e = bid * 256 + tid;
        if (e < NEDGES) atomicAdd(cnt_work + dst[e], 1);
    } else {
        // ---- W convert+transpose (LDS-tiled): Wt[n][k] bf16 ----
        int wb = bid - HIST_BLKS;                     // 0..63
        int kb = (wb & 7) * 32, nb = (wb >> 3) * 32;
        int tx = tid & 31, ty = tid >> 5;
        for (int i = ty; i < 32; i += 8) {
            int k = kb + i, n = nb + tx;
            float v = (n < HD) ? Wsrc[(size_t)k * HD + n] : Wdst[(size_t)k * HD + (n - HD)];
            t[i][tx] = v;
        }
        __syncthreads();
        for (int i = ty; i < 32; i += 8) {
            int n = nb + i, k = kb + tx;
            Wt[(size_t)n * INDIM + k] = f2bf(t[tx][i]);
        }
    }
}

// ================= CSR scans =================
__global__ __launch_bounds__(256) void scan_partial_kernel(
        const int* __restrict__ cnt, int* __restrict__ partials) {
    __shared__ int lds[256];
    int i = blockIdx.x * 256 + threadIdx.x;
    lds[threadIdx.x] = (i < NNODES) ? cnt[i] : 0;
    __syncthreads();
    for (int off = 128; off > 0; off >>= 1) {
        if (threadIdx.x < off) lds[threadIdx.x] += lds[threadIdx.x + off];
        __syncthreads();
    }
    if (threadIdx.x == 0) partials[blockIdx.x] = lds[0];
}

__global__ __launch_bounds__(256) void scan_offsets_kernel(
        int* __restrict__ partials, int* __restrict__ rowptr) {
    __shared__ int lds[256];
    int t = threadIdx.x;
    int v = (t < SCAN_B) ? partials[t] : 0;
    lds[t] = v;
    __syncthreads();
    for (int off = 1; off < 256; off <<= 1) {
        int u = (t >= off) ? lds[t - off] : 0;
        __syncthreads();
        lds[t] += u;
        __syncthreads();
    }
    if (t < SCAN_B) partials[t] = lds[t] - v;      // exclusive
    if (t == 255) rowptr[NNODES] = lds[255];       // total
}

__global__ __launch_bounds__(256) void scan_final_kernel(
        int* __restrict__ cnt_work, const int* __restrict__ partials,
        int* __restrict__ rowptr) {
    __shared__ int lds[256];
    int i = blockIdx.x * 256 + threadIdx.x;
    int t = threadIdx.x;
    int v = (i < NNODES) ? cnt_work[i] : 0;
    lds[t] = v;
    __syncthreads();
    for (int off = 1; off < 256; off <<= 1) {
        int u = (t >= off) ? lds[t - off] : 0;
        __syncthreads();
        lds[t] += u;
        __syncthreads();
    }
    if (i < NNODES) {
        int start = partials[blockIdx.x] + lds[t] - v;
        rowptr[i] = start;
        cnt_work[i] = start;
    }
}

// ================= fusedB: MFMA GEMM (128x256, f32 A direct) | scatter =================
// A is read once (f32 h, converted in staging with f2bf -> bit-identical to the old
// conv_h + bf16-GEMM path). Both el (cols 0..127) and er (cols 128..255) computed
// per block, so the conv_h pass and h_bf buffer are eliminated.
__global__ __launch_bounds__(256, 2) void fusedB_kernel(
        const float* __restrict__ h, const ushort* __restrict__ Wt,
        const float* __restrict__ bsrc, const float* __restrict__ bdst,
        ushort* __restrict__ el_bf, float* __restrict__ er,
        const int* __restrict__ src, const int* __restrict__ dst,
        int* __restrict__ cnt_work, int2* __restrict__ epair) {
    __shared__ ushort As[512 * 8];    // 128 rows x 32 k bf16 (8 KB)
    __shared__ ushort Bs[1024 * 8];   // 256 cols x 32 k bf16 (16 KB)

    const int bid = blockIdx.x;
    const int tid = threadIdx.x;

    if (bid >= GEMM_BLKS) {
        // ---- scatter: build CSR edge list (packed {eidx, esrc} 8B store) ----
        int e = (bid - GEMM_BLKS) * 256 + tid;
        if (e >= NEDGES) return;
        int s = src[e];
        int pos = atomicAdd(cnt_work + dst[e], 1);
        epair[pos] = make_int2(e, s);
        return;
    }

    const int wave = tid >> 6, lane = tid & 63;
    const int row0 = bid * 128;
    const int l15  = lane & 15, quad = lane >> 4;

    floatx4 acc[2][16];
#pragma unroll
    for (int i = 0; i < 2; ++i)
#pragma unroll
        for (int j = 0; j < 16; ++j) acc[i][j] = (floatx4){0.f, 0.f, 0.f, 0.f};

    for (int kk = 0; kk < INDIM; kk += 32) {
        // ---- A staging: 512 chunks of 8, f32 source + convert ----
#pragma unroll
        for (int it = 0; it < 2; ++it) {
            int idx = tid + it * 256;    // 0..511
            int r = idx >> 2;            // 0..127 (row)
            int kq = idx & 3;            // k-quad (8 elems)
            int c = (r >> 4) * 64 + kq * 16 + (r & 15);
            int grow = row0 + r;
            ushort8 aw = (ushort8){0,0,0,0,0,0,0,0};
            if (grow < NNODES) {
                const float* p = h + (size_t)grow * INDIM + kk + kq * 8;
                float4 v0 = *(const float4*)p;
                float4 v1 = *(const float4*)(p + 4);
                aw[0] = f2bf(v0.x); aw[1] = f2bf(v0.y); aw[2] = f2bf(v0.z); aw[3] = f2bf(v0.w);
                aw[4] = f2bf(v1.x); aw[5] = f2bf(v1.y); aw[6] = f2bf(v1.z); aw[7] = f2bf(v1.w);
            }
            *(ushort8*)(As + swz(c) * 8) = aw;
        }
        // ---- B staging: 1024 chunks of 8 (256 cols) ----
#pragma unroll
        for (int it = 0; it < 4; ++it) {
            int idx = tid + it * 256;    // 0..1023
            int r = idx >> 2;            // 0..255 (col)
            int kq = idx & 3;
            int c = (r >> 4) * 64 + kq * 16 + (r & 15);   // 0..1023
            ushort8 bw = *(const ushort8*)(Wt + (size_t)r * INDIM + kk + kq * 8);
            *(ushort8*)(Bs + swz(c) * 8) = bw;
        }
        __syncthreads();

        short8 af[2];
#pragma unroll
        for (int tm = 0; tm < 2; ++tm) {
            int c = (wave * 2 + tm) * 64 + quad * 16 + l15;
            af[tm] = *(const short8*)(As + swz(c) * 8);
        }
#pragma unroll
        for (int tn = 0; tn < 16; ++tn) {
            int c = tn * 64 + quad * 16 + l15;
            short8 bfr = *(const short8*)(Bs + swz(c) * 8);
            acc[0][tn] = __builtin_amdgcn_mfma_f32_16x16x32_bf16(af[0], bfr, acc[0][tn], 0, 0, 0);
            acc[1][tn] = __builtin_amdgcn_mfma_f32_16x16x32_bf16(af[1], bfr, acc[1][tn], 0, 0, 0);
        }
        __syncthreads();
    }

    // epilogue: C/D layout col=lane&15, row=quad*4+reg
#pragma unroll
    for (int tn = 0; tn < 8; ++tn) {
        int col = tn * 16 + l15;              // 0..127 -> el
        float bias = bsrc[col];
#pragma unroll
        for (int tm = 0; tm < 2; ++tm)
#pragma unroll
            for (int reg = 0; reg < 4; ++reg) {
                int row = row0 + wave * 32 + tm * 16 + quad * 4 + reg;
                if (row < NNODES)
                    el_bf[(size_t)row * HD + col] = f2bf(acc[tm][tn][reg] + bias);
            }
    }
#pragma unroll
    for (int tn = 8; tn < 16; ++tn) {
        int col = tn * 16 + l15 - HD;         // 0..127 -> er
        float bias = bdst[col];
#pragma unroll
        for (int tm = 0; tm < 2; ++tm)
#pragma unroll
            for (int reg = 0; reg < 4; ++reg) {
                int row = row0 + wave * 32 + tm * 16 + quad * 4 + reg;
                if (row < NNODES)
                    er[(size_t)row * HD + col] = acc[tm][tn][reg] + bias;
            }
    }
}

// ================= node_fused (round-1 proven structure + sub-chunk softmax) =======
// one wave per node; lane l owns dims 2l,2l+1; head hh = l>>4.
// Indices preloaded 16 at a time (coalesced), broadcast via readlane -> scalar-base
// gathers, 16 loads in flight. Softmax rescale amortized: one max+rescale per
// 4-edge sub-chunk instead of per edge. u[] is ZERO-INITIALIZED so invalid tail
// edges contribute w=0 * finite (uninitialized bf16 garbage can decode to NaN and
// 0*NaN = NaN -- round-3 bug). Raw scores stashed in LDS (cap 128); deg>128 falls
// back to a 2-pass recompute path.
#define DEGCAP 128

__global__ __launch_bounds__(256) void node_fused_kernel(
        const ushort* __restrict__ el_bf, const float* __restrict__ er,
        const int* __restrict__ rowptr, const int2* __restrict__ epair,
        const float* __restrict__ attn,
        float* __restrict__ out_feat, float* __restrict__ out_a) {
    __shared__ float sp[4][DEGCAP * NH];   // 2 KB per wave

    const int wv = threadIdx.x >> 6;
    const int n = blockIdx.x * 4 + wv;
    if (n >= NNODES) return;
    const int lane = threadIdx.x & 63;
    const int hh = lane >> 4;
    const int lo = rowptr[n], hi = rowptr[n + 1];
    const int deg = hi - lo;
    float* spw = sp[wv];
    const int l2 = lane * 2;

    const float2 rv = *(const float2*)(er + (size_t)n * HD + l2);
    const float a0 = attn[l2], a1 = attn[l2 + 1];

    float m = -3.4e38f, lsum = 0.0f, acc0 = 0.0f, acc1 = 0.0f;

    if (deg > 0 && deg <= DEGCAP) {
        // preload first chunk of up to 16 edge-source indices (coalesced, clamped)
        int jj0 = (lane & 15);
        if (jj0 >= deg) jj0 = deg - 1;
        int si = epair[lo + jj0].y;

        for (int base = 0; base < deg; base += 16) {
            // issue all gathers of this chunk (wave-uniform scalar base per edge)
            ushort2 u[16];
#pragma unroll
            for (int j = 0; j < 16; ++j) u[j] = (ushort2){0, 0};   // NaN guard for tail
#pragma unroll
            for (int j = 0; j < 16; ++j) {
                if (base + j < deg) {
                    int s = __builtin_amdgcn_readlane(si, j);
                    u[j] = *(const ushort2*)(el_bf + (size_t)s * HD + l2);
                }
            }
            // prefetch next chunk's indices (hides index-load latency under compute)
            int si_nxt = si;
            if (base + 16 < deg) {
                int jj = base + 16 + (lane & 15);
                if (jj >= deg) jj = deg - 1;
                si_nxt = epair[lo + jj].y;
            }
            // process 4 sub-chunks of 4 edges; one softmax rescale per sub-chunk
#pragma unroll
            for (int g = 0; g < 4; ++g) {
                float px[4], ex[4], ey[4];
#pragma unroll
                for (int j = 0; j < 4; ++j) {
                    int jj = g * 4 + j;
                    bool valid = (base + jj) < deg;
                    float evx = bf2f(u[jj].x), evy = bf2f(u[jj].y);
                    ex[j] = evx; ey[j] = evy;
                    float x0 = evx + rv.x; x0 = fmaxf(x0, NEG * x0);
                    float x1 = evy + rv.y; x1 = fmaxf(x1, NEG * x1);
                    float p = x0 * a0 + x1 * a1;
                    p += __shfl_xor(p, 1, 16);
                    p += __shfl_xor(p, 2, 16);
                    p += __shfl_xor(p, 4, 16);
                    p += __shfl_xor(p, 8, 16);
                    if (valid && (lane & 15) == 0) spw[(base + jj) * NH + hh] = p;
                    px[j] = valid ? p : -3.4e38f;
                }
                float cm = fmaxf(fmaxf(px[0], px[1]), fmaxf(px[2], px[3]));
                float mn = fmaxf(m, cm);
                float sc = __expf(m - mn);
                float w0 = __expf(px[0] - mn);
                float w1 = __expf(px[1] - mn);
                float w2 = __expf(px[2] - mn);
                float w3 = __expf(px[3] - mn);
                lsum = fmaf(lsum, sc, (w0 + w1) + (w2 + w3));
                acc0 *= sc; acc1 *= sc;
                acc0 = fmaf(w0, ex[0], acc0); acc1 = fmaf(w0, ey[0], acc1);
                acc0 = fmaf(w1, ex[1], acc0); acc1 = fmaf(w1, ey[1], acc1);
                acc0 = fmaf(w2, ex[2], acc0); acc1 = fmaf(w2, ey[2], acc1);
                acc0 = fmaf(w3, ex[3], acc0); acc1 = fmaf(w3, ey[3], acc1);
                m = mn;
            }
            si = si_nxt;
        }
    } else if (deg > DEGCAP) {
        // fallback pass 1: online softmax only (no score stash)
        ushort2 u = {0,0};
        { int s_ = epair[lo].y; u = *(const ushort2*)(el_bf + (size_t)s_ * HD + l2); }
        for (int i = lo; i < hi; ++i) {
            float evx = bf2f(u.x), evy = bf2f(u.y);
            if (i + 1 < hi) { int s_ = epair[i + 1].y;
                u = *(const ushort2*)(el_bf + (size_t)s_ * HD + l2); }
            float x0 = evx + rv.x; x0 = fmaxf(x0, NEG * x0);
            float x1 = evy + rv.y; x1 = fmaxf(x1, NEG * x1);
            float p = x0 * a0 + x1 * a1;
            p += __shfl_xor(p, 1, 16);
            p += __shfl_xor(p, 2, 16);
            p += __shfl_xor(p, 4, 16);
            p += __shfl_xor(p, 8, 16);
            float mn = fmaxf(m, p);
            float sc = __expf(m - mn);
            float w  = __expf(p - mn);
            lsum = lsum * sc + w;
            acc0 = acc0 * sc + w * evx;
            acc1 = acc1 * sc + w * evy;
            m = mn;
        }
    }

    // write aggregated features
    float2 o;
    if (deg == 0) { o.x = 0.0f; o.y = 0.0f; }
    else { float inv = 1.0f / lsum; o.x = acc0 * inv; o.y = acc1 * inv; }
    *(float2*)(out_feat + (size_t)n * HD + l2) = o;

    if (deg == 0) return;

    // normalize + write attention weights
    float inv = 1.0f / lsum;
    if (deg <= DEGCAP) {
        // broadcast (m, inv) of head (lane&3) from its group (values uniform in group)
        float mh   = __shfl(m,   (lane & 3) << 4, 64);
        float invh = __shfl(inv, (lane & 3) << 4, 64);
        for (int q = (lane >> 2); q < deg; q += 16) {
            int e = epair[lo + q].x;
            float p = spw[q * NH + (lane & 3)];
            out_a[(size_t)e * NH + (lane & 3)] = __expf(p - mh) * invh;
        }
    } else {
        // fallback pass 2: recompute scores and write a
        for (int i = lo; i < hi; ++i) {
            int s_ = epair[i].y;
            ushort2 u = *(const ushort2*)(el_bf + (size_t)s_ * HD + l2);
            float evx = bf2f(u.x), evy = bf2f(u.y);
            float x0 = evx + rv.x; x0 = fmaxf(x0, NEG * x0);
            float x1 = evy + rv.y; x1 = fmaxf(x1, NEG * x1);
            float p = x0 * a0 + x1 * a1;
            p += __shfl_xor(p, 1, 16);
            p += __shfl_xor(p, 2, 16);
            p += __shfl_xor(p, 4, 16);
            p += __shfl_xor(p, 8, 16);
            if ((lane & 15) == 0) {
                int e = epair[i].x;
                out_a[(size_t)e * NH + hh] = __expf(p - m) * inv;
            }
        }
    }
}

extern "C" void kernel_launch(void* const* d_in, const int* in_sizes, int n_in,
                              void* d_out, int out_size, void* d_ws, size_t ws_size,
                              hipStream_t stream) {
    const float* h    = (const float*)d_in[0];
    const int*   src  = (const int*)d_in[1];
    const int*   dst  = (const int*)d_in[2];
    const float* Wsrc = (const float*)d_in[3];
    const float* bsrc = (const float*)d_in[4];
    const float* Wdst = (const float*)d_in[5];
    const float* bdst = (const float*)d_in[6];
    const float* attn = (const float*)d_in[7];

    float* out_feat = (float*)d_out;                       // N*128
    float* out_a    = out_feat + (size_t)NNODES * HD;      // E*4

    // workspace layout (16B-aligned chunks)
    float*  er       = (float*)d_ws;                         // N*128 f32
    ushort* Wt       = (ushort*)(er + (size_t)NNODES * HD);  // 256*256 bf16
    ushort* el_bf    = Wt + 2 * HD * INDIM;                  // N*128 bf16
    int*    cnt_work = (int*)(el_bf + (size_t)NNODES * HD);  // N
    int2*   epair    = (int2*)(cnt_work + NNODES);           // E  {eidx, esrc}
    int*    rowptr   = (int*)(epair + NEDGES);               // N+1
    int*    partials = rowptr + NNODES + 1;                  // SCAN_B

    hipMemsetAsync(cnt_work, 0, NNODES * sizeof(int), stream);

    // fusedA: dst histogram | W convert+transpose (independent)
    fusedA_kernel<<<HIST_BLKS + CONVW_BLKS, 256, 0, stream>>>(
        dst, cnt_work, Wsrc, Wdst, Wt);

    // CSR prefix-sum chain
    scan_partial_kernel<<<SCAN_B, 256, 0, stream>>>(cnt_work, partials);
    scan_offsets_kernel<<<1, 256, 0, stream>>>(partials, rowptr);
    scan_final_kernel<<<SCAN_B, 256, 0, stream>>>(cnt_work, partials, rowptr);

    // fusedB: MFMA GEMM 128x256 (el+er, f32 A direct) | CSR scatter
    fusedB_kernel<<<GEMM_BLKS + SCAT_BLKS, 256, 0, stream>>>(
        h, Wt, bsrc, bdst, el_bf, er, src, dst, cnt_work, epair);

    node_fused_kernel<<<(NNODES + 3) / 4, 256, 0, stream>>>(
        el_bf, er, rowptr, epair, attn, out_feat, out_a);
}

// Round 5
// 271.720 us; speedup vs baseline: 1.1465x; 1.1232x over previous
//
#include <hip/hip_runtime.h>
#include <cstdint>
#include <cstddef>

#define NNODES 50000
#define NEDGES 800000
#define INDIM  256
#define HD     128   // H*D
#define NH     4
#define NEG    0.2f

#define SCAN_B ((NNODES + 255) / 256)   // 196 blocks

// fusedA block partition (hist | conv_w)
#define HIST_BLKS  ((NEDGES + 255) / 256)           // 3125
#define CONVW_BLKS 64
// fusedB block partition (gemm 128x256 | scatter)
#define GEMM_BLKS  ((NNODES + 127) / 128)           // 391
#define SCAT_BLKS  ((NEDGES + 255) / 256)           // 3125

typedef __attribute__((ext_vector_type(8))) short   short8;   // 8 bf16 (4 VGPRs)
typedef __attribute__((ext_vector_type(8))) ushort  ushort8;
typedef __attribute__((ext_vector_type(4))) float   floatx4;

// f32 -> bf16 (round-to-nearest-even), raw bits
__device__ __forceinline__ ushort f2bf(float f) {
    unsigned u = __float_as_uint(f);
    unsigned r = u + 0x7fffu + ((u >> 16) & 1u);
    return (ushort)(r >> 16);
}
__device__ __forceinline__ float bf2f(ushort u) {
    return __uint_as_float(((unsigned)u) << 16);
}

// LDS chunk swizzle: conflict-free staging writes + fragment reads
__device__ __forceinline__ int swz(int c) { return c ^ ((c >> 4) & 7); }

// ================= fusedA: hist | conv_w  (independent) =================
__global__ __launch_bounds__(256) void fusedA_kernel(
        const int* __restrict__ dst, int* __restrict__ cnt_work,
        const float* __restrict__ Wsrc, const float* __restrict__ Wdst,
        ushort* __restrict__ Wt) {
    __shared__ float t[32][33];
    const int bid = blockIdx.x;
    const int tid = threadIdx.x;

    if (bid < HIST_BLKS) {
        // ---- histogram of dst ----
        int e = bid * 256 + tid;
        if (e < NEDGES) atomicAdd(cnt_work + dst[e], 1);
    } else {
        // ---- W convert+transpose (LDS-tiled): Wt[n][k] bf16 ----
        int wb = bid - HIST_BLKS;                     // 0..63
        int kb = (wb & 7) * 32, nb = (wb >> 3) * 32;
        int tx = tid & 31, ty = tid >> 5;
        for (int i = ty; i < 32; i += 8) {
            int k = kb + i, n = nb + tx;
            float v = (n < HD) ? Wsrc[(size_t)k * HD + n] : Wdst[(size_t)k * HD + (n - HD)];
            t[i][tx] = v;
        }
        __syncthreads();
        for (int i = ty; i < 32; i += 8) {
            int n = nb + i, k = kb + tx;
            Wt[(size_t)n * INDIM + k] = f2bf(t[tx][i]);
        }
    }
}

// ================= CSR scans =================
__global__ __launch_bounds__(256) void scan_partial_kernel(
        const int* __restrict__ cnt, int* __restrict__ partials) {
    __shared__ int lds[256];
    int i = blockIdx.x * 256 + threadIdx.x;
    lds[threadIdx.x] = (i < NNODES) ? cnt[i] : 0;
    __syncthreads();
    for (int off = 128; off > 0; off >>= 1) {
        if (threadIdx.x < off) lds[threadIdx.x] += lds[threadIdx.x + off];
        __syncthreads();
    }
    if (threadIdx.x == 0) partials[blockIdx.x] = lds[0];
}

__global__ __launch_bounds__(256) void scan_offsets_kernel(
        int* __restrict__ partials, int* __restrict__ rowptr) {
    __shared__ int lds[256];
    int t = threadIdx.x;
    int v = (t < SCAN_B) ? partials[t] : 0;
    lds[t] = v;
    __syncthreads();
    for (int off = 1; off < 256; off <<= 1) {
        int u = (t >= off) ? lds[t - off] : 0;
        __syncthreads();
        lds[t] += u;
        __syncthreads();
    }
    if (t < SCAN_B) partials[t] = lds[t] - v;      // exclusive
    if (t == 255) rowptr[NNODES] = lds[255];       // total
}

__global__ __launch_bounds__(256) void scan_final_kernel(
        int* __restrict__ cnt_work, const int* __restrict__ partials,
        int* __restrict__ rowptr) {
    __shared__ int lds[256];
    int i = blockIdx.x * 256 + threadIdx.x;
    int t = threadIdx.x;
    int v = (i < NNODES) ? cnt_work[i] : 0;
    lds[t] = v;
    __syncthreads();
    for (int off = 1; off < 256; off <<= 1) {
        int u = (t >= off) ? lds[t - off] : 0;
        __syncthreads();
        lds[t] += u;
        __syncthreads();
    }
    if (i < NNODES) {
        int start = partials[blockIdx.x] + lds[t] - v;
        rowptr[i] = start;
        cnt_work[i] = start;
    }
}

// ================= fusedB: MFMA GEMM (128x256, f32 A direct) | scatter =================
// A is read once (f32 h, converted in staging with f2bf -> bit-identical to the old
// conv_h + bf16-GEMM path). Both el (cols 0..127) and er (cols 128..255) computed
// per block, so the conv_h pass and h_bf buffer are eliminated.
__global__ __launch_bounds__(256, 2) void fusedB_kernel(
        const float* __restrict__ h, const ushort* __restrict__ Wt,
        const float* __restrict__ bsrc, const float* __restrict__ bdst,
        ushort* __restrict__ el_bf, float* __restrict__ er,
        const int* __restrict__ src, const int* __restrict__ dst,
        int* __restrict__ cnt_work, int2* __restrict__ epair) {
    __shared__ ushort As[512 * 8];    // 128 rows x 32 k bf16 (8 KB)
    __shared__ ushort Bs[1024 * 8];   // 256 cols x 32 k bf16 (16 KB)

    const int bid = blockIdx.x;
    const int tid = threadIdx.x;

    if (bid >= GEMM_BLKS) {
        // ---- scatter: build CSR edge list (packed {eidx, esrc} 8B store) ----
        int e = (bid - GEMM_BLKS) * 256 + tid;
        if (e >= NEDGES) return;
        int s = src[e];
        int pos = atomicAdd(cnt_work + dst[e], 1);
        epair[pos] = make_int2(e, s);
        return;
    }

    const int wave = tid >> 6, lane = tid & 63;
    const int row0 = bid * 128;
    const int l15  = lane & 15, quad = lane >> 4;

    floatx4 acc[2][16];
#pragma unroll
    for (int i = 0; i < 2; ++i)
#pragma unroll
        for (int j = 0; j < 16; ++j) acc[i][j] = (floatx4){0.f, 0.f, 0.f, 0.f};

    for (int kk = 0; kk < INDIM; kk += 32) {
        // ---- A staging: 512 chunks of 8, f32 source + convert ----
#pragma unroll
        for (int it = 0; it < 2; ++it) {
            int idx = tid + it * 256;    // 0..511
            int r = idx >> 2;            // 0..127 (row)
            int kq = idx & 3;            // k-quad (8 elems)
            int c = (r >> 4) * 64 + kq * 16 + (r & 15);
            int grow = row0 + r;
            ushort8 aw = (ushort8){0,0,0,0,0,0,0,0};
            if (grow < NNODES) {
                const float* p = h + (size_t)grow * INDIM + kk + kq * 8;
                float4 v0 = *(const float4*)p;
                float4 v1 = *(const float4*)(p + 4);
                aw[0] = f2bf(v0.x); aw[1] = f2bf(v0.y); aw[2] = f2bf(v0.z); aw[3] = f2bf(v0.w);
                aw[4] = f2bf(v1.x); aw[5] = f2bf(v1.y); aw[6] = f2bf(v1.z); aw[7] = f2bf(v1.w);
            }
            *(ushort8*)(As + swz(c) * 8) = aw;
        }
        // ---- B staging: 1024 chunks of 8 (256 cols) ----
#pragma unroll
        for (int it = 0; it < 4; ++it) {
            int idx = tid + it * 256;    // 0..1023
            int r = idx >> 2;            // 0..255 (col)
            int kq = idx & 3;
            int c = (r >> 4) * 64 + kq * 16 + (r & 15);   // 0..1023
            ushort8 bw = *(const ushort8*)(Wt + (size_t)r * INDIM + kk + kq * 8);
            *(ushort8*)(Bs + swz(c) * 8) = bw;
        }
        __syncthreads();

        short8 af[2];
#pragma unroll
        for (int tm = 0; tm < 2; ++tm) {
            int c = (wave * 2 + tm) * 64 + quad * 16 + l15;
            af[tm] = *(const short8*)(As + swz(c) * 8);
        }
#pragma unroll
        for (int tn = 0; tn < 16; ++tn) {
            int c = tn * 64 + quad * 16 + l15;
            short8 bfr = *(const short8*)(Bs + swz(c) * 8);
            acc[0][tn] = __builtin_amdgcn_mfma_f32_16x16x32_bf16(af[0], bfr, acc[0][tn], 0, 0, 0);
            acc[1][tn] = __builtin_amdgcn_mfma_f32_16x16x32_bf16(af[1], bfr, acc[1][tn], 0, 0, 0);
        }
        __syncthreads();
    }

    // epilogue: C/D layout col=lane&15, row=quad*4+reg
#pragma unroll
    for (int tn = 0; tn < 8; ++tn) {
        int col = tn * 16 + l15;              // 0..127 -> el
        float bias = bsrc[col];
#pragma unroll
        for (int tm = 0; tm < 2; ++tm)
#pragma unroll
            for (int reg = 0; reg < 4; ++reg) {
                int row = row0 + wave * 32 + tm * 16 + quad * 4 + reg;
                if (row < NNODES)
                    el_bf[(size_t)row * HD + col] = f2bf(acc[tm][tn][reg] + bias);
            }
    }
#pragma unroll
    for (int tn = 8; tn < 16; ++tn) {
        int col = tn * 16 + l15 - HD;         // 0..127 -> er
        float bias = bdst[col];
#pragma unroll
        for (int tm = 0; tm < 2; ++tm)
#pragma unroll
            for (int reg = 0; reg < 4; ++reg) {
                int row = row0 + wave * 32 + tm * 16 + quad * 4 + reg;
                if (row < NNODES)
                    er[(size_t)row * HD + col] = acc[tm][tn][reg] + bias;
            }
    }
}

// ================= node_fused: round-1 proven body (71us) + defer-max =================
// one wave per node; lane l owns dims 2l,2l+1; head hh = l>>4.
// Indices preloaded 16 at a time (coalesced), broadcast via readlane -> scalar-base
// gathers, 16 loads in flight; per-edge processing (do NOT restructure: two batched
// rewrites of this loop both regressed ~45% -- the compiler's incremental vmcnt
// pipelining of this exact shape is load-bearing). Defer-max: p,m uniform per
// 16-lane group, so (p>m) is a group-uniform short branch; common path is
// 1 exp + 3 fma (no rescale). Semantics exact. Scores stashed in LDS (cap 128);
// deg>128 falls back to a 2-pass recompute path.
#define DEGCAP 128

__global__ __launch_bounds__(256) void node_fused_kernel(
        const ushort* __restrict__ el_bf, const float* __restrict__ er,
        const int* __restrict__ rowptr, const int2* __restrict__ epair,
        const float* __restrict__ attn,
        float* __restrict__ out_feat, float* __restrict__ out_a) {
    __shared__ float sp[4][DEGCAP * NH];   // 2 KB per wave

    const int wv = threadIdx.x >> 6;
    const int n = blockIdx.x * 4 + wv;
    if (n >= NNODES) return;
    const int lane = threadIdx.x & 63;
    const int hh = lane >> 4;
    const int lo = rowptr[n], hi = rowptr[n + 1];
    const int deg = hi - lo;
    float* spw = sp[wv];
    const int l2 = lane * 2;

    const float2 rv = *(const float2*)(er + (size_t)n * HD + l2);
    const float a0 = attn[l2], a1 = attn[l2 + 1];

    float m = -3.4e38f, lsum = 0.0f, acc0 = 0.0f, acc1 = 0.0f;

    if (deg > 0 && deg <= DEGCAP) {
        // preload first chunk of up to 16 edge-source indices (coalesced, clamped)
        int jj0 = (lane & 15);
        if (jj0 >= deg) jj0 = deg - 1;
        int si = epair[lo + jj0].y;

        for (int base = 0; base < deg; base += 16) {
            // issue all gathers of this chunk (wave-uniform scalar base per edge)
            ushort2 u[16];
#pragma unroll
            for (int j = 0; j < 16; ++j) {
                if (base + j < deg) {
                    int s = __builtin_amdgcn_readlane(si, j);
                    u[j] = *(const ushort2*)(el_bf + (size_t)s * HD + l2);
                }
            }
            // prefetch next chunk's indices (hides index-load latency under compute)
            int si_nxt = si;
            if (base + 16 < deg) {
                int jj = base + 16 + (lane & 15);
                if (jj >= deg) jj = deg - 1;
                si_nxt = epair[lo + jj].y;
            }
            // process chunk: per-edge, exec-masked tail (round-1 proven shape)
#pragma unroll
            for (int j = 0; j < 16; ++j) {
                if (base + j < deg) {
                    float evx = bf2f(u[j].x), evy = bf2f(u[j].y);
                    float x0 = evx + rv.x; x0 = fmaxf(x0, NEG * x0);
                    float x1 = evy + rv.y; x1 = fmaxf(x1, NEG * x1);
                    float p = x0 * a0 + x1 * a1;
                    p += __shfl_xor(p, 1, 16);
                    p += __shfl_xor(p, 2, 16);
                    p += __shfl_xor(p, 4, 16);
                    p += __shfl_xor(p, 8, 16);
                    if ((lane & 15) == 0) spw[(base + j) * NH + hh] = p;
                    // defer-max online softmax (group-uniform branch)
                    if (p > m) {
                        float sc = __expf(m - p);      // w = exp(p-p) = 1
                        lsum = fmaf(lsum, sc, 1.0f);
                        acc0 = fmaf(acc0, sc, evx);
                        acc1 = fmaf(acc1, sc, evy);
                        m = p;
                    } else {
                        float w = __expf(p - m);
                        lsum += w;
                        acc0 = fmaf(w, evx, acc0);
                        acc1 = fmaf(w, evy, acc1);
                    }
                }
            }
            si = si_nxt;
        }
    } else if (deg > DEGCAP) {
        // fallback pass 1: online softmax only (no score stash)
        ushort2 u = {0,0};
        { int s_ = epair[lo].y; u = *(const ushort2*)(el_bf + (size_t)s_ * HD + l2); }
        for (int i = lo; i < hi; ++i) {
            float evx = bf2f(u.x), evy = bf2f(u.y);
            if (i + 1 < hi) { int s_ = epair[i + 1].y;
                u = *(const ushort2*)(el_bf + (size_t)s_ * HD + l2); }
            float x0 = evx + rv.x; x0 = fmaxf(x0, NEG * x0);
            float x1 = evy + rv.y; x1 = fmaxf(x1, NEG * x1);
            float p = x0 * a0 + x1 * a1;
            p += __shfl_xor(p, 1, 16);
            p += __shfl_xor(p, 2, 16);
            p += __shfl_xor(p, 4, 16);
            p += __shfl_xor(p, 8, 16);
            float mn = fmaxf(m, p);
            float sc = __expf(m - mn);
            float w  = __expf(p - mn);
            lsum = lsum * sc + w;
            acc0 = acc0 * sc + w * evx;
            acc1 = acc1 * sc + w * evy;
            m = mn;
        }
    }

    // write aggregated features
    float2 o;
    if (deg == 0) { o.x = 0.0f; o.y = 0.0f; }
    else { float inv = 1.0f / lsum; o.x = acc0 * inv; o.y = acc1 * inv; }
    *(float2*)(out_feat + (size_t)n * HD + l2) = o;

    if (deg == 0) return;

    // normalize + write attention weights
    float inv = 1.0f / lsum;
    if (deg <= DEGCAP) {
        // broadcast (m, inv) of head (lane&3) from its group (values uniform in group)
        float mh   = __shfl(m,   (lane & 3) << 4, 64);
        float invh = __shfl(inv, (lane & 3) << 4, 64);
        for (int q = (lane >> 2); q < deg; q += 16) {
            int e = epair[lo + q].x;
            float p = spw[q * NH + (lane & 3)];
            out_a[(size_t)e * NH + (lane & 3)] = __expf(p - mh) * invh;
        }
    } else {
        // fallback pass 2: recompute scores and write a
        for (int i = lo; i < hi; ++i) {
            int s_ = epair[i].y;
            ushort2 u = *(const ushort2*)(el_bf + (size_t)s_ * HD + l2);
            float evx = bf2f(u.x), evy = bf2f(u.y);
            float x0 = evx + rv.x; x0 = fmaxf(x0, NEG * x0);
            float x1 = evy + rv.y; x1 = fmaxf(x1, NEG * x1);
            float p = x0 * a0 + x1 * a1;
            p += __shfl_xor(p, 1, 16);
            p += __shfl_xor(p, 2, 16);
            p += __shfl_xor(p, 4, 16);
            p += __shfl_xor(p, 8, 16);
            if ((lane & 15) == 0) {
                int e = epair[i].x;
                out_a[(size_t)e * NH + hh] = __expf(p - m) * inv;
            }
        }
    }
}

extern "C" void kernel_launch(void* const* d_in, const int* in_sizes, int n_in,
                              void* d_out, int out_size, void* d_ws, size_t ws_size,
                              hipStream_t stream) {
    const float* h    = (const float*)d_in[0];
    const int*   src  = (const int*)d_in[1];
    const int*   dst  = (const int*)d_in[2];
    const float* Wsrc = (const float*)d_in[3];
    const float* bsrc = (const float*)d_in[4];
    const float* Wdst = (const float*)d_in[5];
    const float* bdst = (const float*)d_in[6];
    const float* attn = (const float*)d_in[7];

    float* out_feat = (float*)d_out;                       // N*128
    float* out_a    = out_feat + (size_t)NNODES * HD;      // E*4

    // workspace layout (16B-aligned chunks)
    float*  er       = (float*)d_ws;                         // N*128 f32
    ushort* Wt       = (ushort*)(er + (size_t)NNODES * HD);  // 256*256 bf16
    ushort* el_bf    = Wt + 2 * HD * INDIM;                  // N*128 bf16
    int*    cnt_work = (int*)(el_bf + (size_t)NNODES * HD);  // N
    int2*   epair    = (int2*)(cnt_work + NNODES);           // E  {eidx, esrc}
    int*    rowptr   = (int*)(epair + NEDGES);               // N+1
    int*    partials = rowptr + NNODES + 1;                  // SCAN_B

    hipMemsetAsync(cnt_work, 0, NNODES * sizeof(int), stream);

    // fusedA: dst histogram | W convert+transpose (independent)
    fusedA_kernel<<<HIST_BLKS + CONVW_BLKS, 256, 0, stream>>>(
        dst, cnt_work, Wsrc, Wdst, Wt);

    // CSR prefix-sum chain
    scan_partial_kernel<<<SCAN_B, 256, 0, stream>>>(cnt_work, partials);
    scan_offsets_kernel<<<1, 256, 0, stream>>>(partials, rowptr);
    scan_final_kernel<<<SCAN_B, 256, 0, stream>>>(cnt_work, partials, rowptr);

    // fusedB: MFMA GEMM 128x256 (el+er, f32 A direct) | CSR scatter
    fusedB_kernel<<<GEMM_BLKS + SCAT_BLKS, 256, 0, stream>>>(
        h, Wt, bsrc, bdst, el_bf, er, src, dst, cnt_work, epair);

    node_fused_kernel<<<(NNODES + 3) / 4, 256, 0, stream>>>(
        el_bf, er, rowptr, epair, attn, out_feat, out_a);
}

// Round 6
// 268.635 us; speedup vs baseline: 1.1596x; 1.0115x over previous
//
#include <hip/hip_runtime.h>
#include <cstdint>
#include <cstddef>

#define NNODES 50000
#define NEDGES 800000
#define INDIM  256
#define HD     128   // H*D
#define NH     4
#define NEG    0.2f

#define SCAN_B ((NNODES + 255) / 256)   // 196 blocks

// fusedA block partition (hist 8 edges/thread | conv_w)
#define HIST_BLKS  ((NEDGES + 2047) / 2048)         // 391
#define CONVW_BLKS 64
// fusedB block partition (gemm 128x256 | scatter 8 edges/thread)
#define GEMM_BLKS  ((NNODES + 127) / 128)           // 391
#define SCAT_BLKS  ((NEDGES + 2047) / 2048)         // 391

typedef __attribute__((ext_vector_type(8))) short   short8;   // 8 bf16 (4 VGPRs)
typedef __attribute__((ext_vector_type(8))) ushort  ushort8;
typedef __attribute__((ext_vector_type(4))) float   floatx4;

// f32 -> bf16 (round-to-nearest-even), raw bits
__device__ __forceinline__ ushort f2bf(float f) {
    unsigned u = __float_as_uint(f);
    unsigned r = u + 0x7fffu + ((u >> 16) & 1u);
    return (ushort)(r >> 16);
}
__device__ __forceinline__ float bf2f(ushort u) {
    return __uint_as_float(((unsigned)u) << 16);
}

// LDS chunk swizzle: conflict-free staging writes + fragment reads
__device__ __forceinline__ int swz(int c) { return c ^ ((c >> 4) & 7); }

// ================= fusedA: hist (8/thread ILP) | conv_w  (independent) =================
__global__ __launch_bounds__(256) void fusedA_kernel(
        const int* __restrict__ dst, int* __restrict__ cnt_work,
        const float* __restrict__ Wsrc, const float* __restrict__ Wdst,
        ushort* __restrict__ Wt) {
    __shared__ float t[32][33];
    const int bid = blockIdx.x;
    const int tid = threadIdx.x;

    if (bid < HIST_BLKS) {
        // ---- histogram of dst: 8 edges/thread, stride-256 (coalesced), 8 atomics in flight
        int base = bid * 2048 + tid;
        int dd[8];
#pragma unroll
        for (int k = 0; k < 8; ++k) {
            int e = base + k * 256;
            dd[k] = (e < NEDGES) ? dst[e] : -1;
        }
#pragma unroll
        for (int k = 0; k < 8; ++k) {
            if (dd[k] >= 0) atomicAdd(cnt_work + dd[k], 1);
        }
    } else {
        // ---- W convert+transpose (LDS-tiled): Wt[n][k] bf16 ----
        int wb = bid - HIST_BLKS;                     // 0..63
        int kb = (wb & 7) * 32, nb = (wb >> 3) * 32;
        int tx = tid & 31, ty = tid >> 5;
        for (int i = ty; i < 32; i += 8) {
            int k = kb + i, n = nb + tx;
            float v = (n < HD) ? Wsrc[(size_t)k * HD + n] : Wdst[(size_t)k * HD + (n - HD)];
            t[i][tx] = v;
        }
        __syncthreads();
        for (int i = ty; i < 32; i += 8) {
            int n = nb + i, k = kb + tx;
            Wt[(size_t)n * INDIM + k] = f2bf(t[tx][i]);
        }
    }
}

// ================= CSR scans =================
__global__ __launch_bounds__(256) void scan_partial_kernel(
        const int* __restrict__ cnt, int* __restrict__ partials) {
    __shared__ int lds[256];
    int i = blockIdx.x * 256 + threadIdx.x;
    lds[threadIdx.x] = (i < NNODES) ? cnt[i] : 0;
    __syncthreads();
    for (int off = 128; off > 0; off >>= 1) {
        if (threadIdx.x < off) lds[threadIdx.x] += lds[threadIdx.x + off];
        __syncthreads();
    }
    if (threadIdx.x == 0) partials[blockIdx.x] = lds[0];
}

__global__ __launch_bounds__(256) void scan_offsets_kernel(
        int* __restrict__ partials, int* __restrict__ rowptr) {
    __shared__ int lds[256];
    int t = threadIdx.x;
    int v = (t < SCAN_B) ? partials[t] : 0;
    lds[t] = v;
    __syncthreads();
    for (int off = 1; off < 256; off <<= 1) {
        int u = (t >= off) ? lds[t - off] : 0;
        __syncthreads();
        lds[t] += u;
        __syncthreads();
    }
    if (t < SCAN_B) partials[t] = lds[t] - v;      // exclusive
    if (t == 255) rowptr[NNODES] = lds[255];       // total
}

__global__ __launch_bounds__(256) void scan_final_kernel(
        int* __restrict__ cnt_work, const int* __restrict__ partials,
        int* __restrict__ rowptr) {
    __shared__ int lds[256];
    int i = blockIdx.x * 256 + threadIdx.x;
    int t = threadIdx.x;
    int v = (i < NNODES) ? cnt_work[i] : 0;
    lds[t] = v;
    __syncthreads();
    for (int off = 1; off < 256; off <<= 1) {
        int u = (t >= off) ? lds[t - off] : 0;
        __syncthreads();
        lds[t] += u;
        __syncthreads();
    }
    if (i < NNODES) {
        int start = partials[blockIdx.x] + lds[t] - v;
        rowptr[i] = start;
        cnt_work[i] = start;
    }
}

// ================= fusedB: MFMA GEMM (128x256, f32 A direct) | scatter (8/thread) =====
// A is read once (f32 h, converted in staging with f2bf -> bit-identical results).
// Scatter: 8 edges/thread -> 8 independent returning-atomic chains in flight
// (the single-chain version was latency-bound: all pipes idle at 80us).
__global__ __launch_bounds__(256, 2) void fusedB_kernel(
        const float* __restrict__ h, const ushort* __restrict__ Wt,
        const float* __restrict__ bsrc, const float* __restrict__ bdst,
        ushort* __restrict__ el_bf, float* __restrict__ er,
        const int* __restrict__ src, const int* __restrict__ dst,
        int* __restrict__ cnt_work, int2* __restrict__ epair) {
    __shared__ ushort As[512 * 8];    // 128 rows x 32 k bf16 (8 KB)
    __shared__ ushort Bs[1024 * 8];   // 256 cols x 32 k bf16 (16 KB)

    const int bid = blockIdx.x;
    const int tid = threadIdx.x;

    if (bid >= GEMM_BLKS) {
        // ---- scatter: build CSR edge list, 8 edges/thread (stride-256, coalesced) ----
        int base = (bid - GEMM_BLKS) * 2048 + tid;
        int ss[8], dd[8], pos[8];
#pragma unroll
        for (int k = 0; k < 8; ++k) {
            int e = base + k * 256;
            if (e < NEDGES) { ss[k] = src[e]; dd[k] = dst[e]; } else dd[k] = -1;
        }
#pragma unroll
        for (int k = 0; k < 8; ++k) {
            if (dd[k] >= 0) pos[k] = atomicAdd(cnt_work + dd[k], 1);
        }
#pragma unroll
        for (int k = 0; k < 8; ++k) {
            int e = base + k * 256;
            if (dd[k] >= 0) epair[pos[k]] = make_int2(e, ss[k]);
        }
        return;
    }

    const int wave = tid >> 6, lane = tid & 63;
    const int row0 = bid * 128;
    const int l15  = lane & 15, quad = lane >> 4;

    floatx4 acc[2][16];
#pragma unroll
    for (int i = 0; i < 2; ++i)
#pragma unroll
        for (int j = 0; j < 16; ++j) acc[i][j] = (floatx4){0.f, 0.f, 0.f, 0.f};

    for (int kk = 0; kk < INDIM; kk += 32) {
        // ---- A staging: 512 chunks of 8, f32 source + convert ----
#pragma unroll
        for (int it = 0; it < 2; ++it) {
            int idx = tid + it * 256;    // 0..511
            int r = idx >> 2;            // 0..127 (row)
            int kq = idx & 3;            // k-quad (8 elems)
            int c = (r >> 4) * 64 + kq * 16 + (r & 15);
            int grow = row0 + r;
            ushort8 aw = (ushort8){0,0,0,0,0,0,0,0};
            if (grow < NNODES) {
                const float* p = h + (size_t)grow * INDIM + kk + kq * 8;
                float4 v0 = *(const float4*)p;
                float4 v1 = *(const float4*)(p + 4);
                aw[0] = f2bf(v0.x); aw[1] = f2bf(v0.y); aw[2] = f2bf(v0.z); aw[3] = f2bf(v0.w);
                aw[4] = f2bf(v1.x); aw[5] = f2bf(v1.y); aw[6] = f2bf(v1.z); aw[7] = f2bf(v1.w);
            }
            *(ushort8*)(As + swz(c) * 8) = aw;
        }
        // ---- B staging: 1024 chunks of 8 (256 cols) ----
#pragma unroll
        for (int it = 0; it < 4; ++it) {
            int idx = tid + it * 256;    // 0..1023
            int r = idx >> 2;            // 0..255 (col)
            int kq = idx & 3;
            int c = (r >> 4) * 64 + kq * 16 + (r & 15);   // 0..1023
            ushort8 bw = *(const ushort8*)(Wt + (size_t)r * INDIM + kk + kq * 8);
            *(ushort8*)(Bs + swz(c) * 8) = bw;
        }
        __syncthreads();

        short8 af[2];
#pragma unroll
        for (int tm = 0; tm < 2; ++tm) {
            int c = (wave * 2 + tm) * 64 + quad * 16 + l15;
            af[tm] = *(const short8*)(As + swz(c) * 8);
        }
#pragma unroll
        for (int tn = 0; tn < 16; ++tn) {
            int c = tn * 64 + quad * 16 + l15;
            short8 bfr = *(const short8*)(Bs + swz(c) * 8);
            acc[0][tn] = __builtin_amdgcn_mfma_f32_16x16x32_bf16(af[0], bfr, acc[0][tn], 0, 0, 0);
            acc[1][tn] = __builtin_amdgcn_mfma_f32_16x16x32_bf16(af[1], bfr, acc[1][tn], 0, 0, 0);
        }
        __syncthreads();
    }

    // epilogue: C/D layout col=lane&15, row=quad*4+reg
#pragma unroll
    for (int tn = 0; tn < 8; ++tn) {
        int col = tn * 16 + l15;              // 0..127 -> el
        float bias = bsrc[col];
#pragma unroll
        for (int tm = 0; tm < 2; ++tm)
#pragma unroll
            for (int reg = 0; reg < 4; ++reg) {
                int row = row0 + wave * 32 + tm * 16 + quad * 4 + reg;
                if (row < NNODES)
                    el_bf[(size_t)row * HD + col] = f2bf(acc[tm][tn][reg] + bias);
            }
    }
#pragma unroll
    for (int tn = 8; tn < 16; ++tn) {
        int col = tn * 16 + l15 - HD;         // 0..127 -> er
        float bias = bdst[col];
#pragma unroll
        for (int tm = 0; tm < 2; ++tm)
#pragma unroll
            for (int reg = 0; reg < 4; ++reg) {
                int row = row0 + wave * 32 + tm * 16 + quad * 4 + reg;
                if (row < NNODES)
                    er[(size_t)row * HD + col] = acc[tm][tn][reg] + bias;
            }
    }
}

// ================= node_fused: round-1 proven body + defer-max (UNCHANGED) =================
// one wave per node; lane l owns dims 2l,2l+1; head hh = l>>4.
// Indices preloaded 16 at a time (coalesced), broadcast via readlane -> scalar-base
// gathers, 16 loads in flight; per-edge processing (do NOT restructure: two batched
// rewrites of this loop both regressed ~45% -- the compiler's incremental vmcnt
// pipelining of this exact shape is load-bearing). Defer-max: p,m uniform per
// 16-lane group, so (p>m) is a group-uniform short branch; common path is
// 1 exp + 3 fma (no rescale). Semantics exact. Scores stashed in LDS (cap 128);
// deg>128 falls back to a 2-pass recompute path.
#define DEGCAP 128

__global__ __launch_bounds__(256) void node_fused_kernel(
        const ushort* __restrict__ el_bf, const float* __restrict__ er,
        const int* __restrict__ rowptr, const int2* __restrict__ epair,
        const float* __restrict__ attn,
        float* __restrict__ out_feat, float* __restrict__ out_a) {
    __shared__ float sp[4][DEGCAP * NH];   // 2 KB per wave

    const int wv = threadIdx.x >> 6;
    const int n = blockIdx.x * 4 + wv;
    if (n >= NNODES) return;
    const int lane = threadIdx.x & 63;
    const int hh = lane >> 4;
    const int lo = rowptr[n], hi = rowptr[n + 1];
    const int deg = hi - lo;
    float* spw = sp[wv];
    const int l2 = lane * 2;

    const float2 rv = *(const float2*)(er + (size_t)n * HD + l2);
    const float a0 = attn[l2], a1 = attn[l2 + 1];

    float m = -3.4e38f, lsum = 0.0f, acc0 = 0.0f, acc1 = 0.0f;

    if (deg > 0 && deg <= DEGCAP) {
        // preload first chunk of up to 16 edge-source indices (coalesced, clamped)
        int jj0 = (lane & 15);
        if (jj0 >= deg) jj0 = deg - 1;
        int si = epair[lo + jj0].y;

        for (int base = 0; base < deg; base += 16) {
            // issue all gathers of this chunk (wave-uniform scalar base per edge)
            ushort2 u[16];
#pragma unroll
            for (int j = 0; j < 16; ++j) {
                if (base + j < deg) {
                    int s = __builtin_amdgcn_readlane(si, j);
                    u[j] = *(const ushort2*)(el_bf + (size_t)s * HD + l2);
                }
            }
            // prefetch next chunk's indices (hides index-load latency under compute)
            int si_nxt = si;
            if (base + 16 < deg) {
                int jj = base + 16 + (lane & 15);
                if (jj >= deg) jj = deg - 1;
                si_nxt = epair[lo + jj].y;
            }
            // process chunk: per-edge, exec-masked tail (round-1 proven shape)
#pragma unroll
            for (int j = 0; j < 16; ++j) {
                if (base + j < deg) {
                    float evx = bf2f(u[j].x), evy = bf2f(u[j].y);
                    float x0 = evx + rv.x; x0 = fmaxf(x0, NEG * x0);
                    float x1 = evy + rv.y; x1 = fmaxf(x1, NEG * x1);
                    float p = x0 * a0 + x1 * a1;
                    p += __shfl_xor(p, 1, 16);
                    p += __shfl_xor(p, 2, 16);
                    p += __shfl_xor(p, 4, 16);
                    p += __shfl_xor(p, 8, 16);
                    if ((lane & 15) == 0) spw[(base + j) * NH + hh] = p;
                    // defer-max online softmax (group-uniform branch)
                    if (p > m) {
                        float sc = __expf(m - p);      // w = exp(p-p) = 1
                        lsum = fmaf(lsum, sc, 1.0f);
                        acc0 = fmaf(acc0, sc, evx);
                        acc1 = fmaf(acc1, sc, evy);
                        m = p;
                    } else {
                        float w = __expf(p - m);
                        lsum += w;
                        acc0 = fmaf(w, evx, acc0);
                        acc1 = fmaf(w, evy, acc1);
                    }
                }
            }
            si = si_nxt;
        }
    } else if (deg > DEGCAP) {
        // fallback pass 1: online softmax only (no score stash)
        ushort2 u = {0,0};
        { int s_ = epair[lo].y; u = *(const ushort2*)(el_bf + (size_t)s_ * HD + l2); }
        for (int i = lo; i < hi; ++i) {
            float evx = bf2f(u.x), evy = bf2f(u.y);
            if (i + 1 < hi) { int s_ = epair[i + 1].y;
                u = *(const ushort2*)(el_bf + (size_t)s_ * HD + l2); }
            float x0 = evx + rv.x; x0 = fmaxf(x0, NEG * x0);
            float x1 = evy + rv.y; x1 = fmaxf(x1, NEG * x1);
            float p = x0 * a0 + x1 * a1;
            p += __shfl_xor(p, 1, 16);
            p += __shfl_xor(p, 2, 16);
            p += __shfl_xor(p, 4, 16);
            p += __shfl_xor(p, 8, 16);
            float mn = fmaxf(m, p);
            float sc = __expf(m - mn);
            float w  = __expf(p - mn);
            lsum = lsum * sc + w;
            acc0 = acc0 * sc + w * evx;
            acc1 = acc1 * sc + w * evy;
            m = mn;
        }
    }

    // write aggregated features
    float2 o;
    if (deg == 0) { o.x = 0.0f; o.y = 0.0f; }
    else { float inv = 1.0f / lsum; o.x = acc0 * inv; o.y = acc1 * inv; }
    *(float2*)(out_feat + (size_t)n * HD + l2) = o;

    if (deg == 0) return;

    // normalize + write attention weights
    float inv = 1.0f / lsum;
    if (deg <= DEGCAP) {
        // broadcast (m, inv) of head (lane&3) from its group (values uniform in group)
        float mh   = __shfl(m,   (lane & 3) << 4, 64);
        float invh = __shfl(inv, (lane & 3) << 4, 64);
        for (int q = (lane >> 2); q < deg; q += 16) {
            int e = epair[lo + q].x;
            float p = spw[q * NH + (lane & 3)];
            out_a[(size_t)e * NH + (lane & 3)] = __expf(p - mh) * invh;
        }
    } else {
        // fallback pass 2: recompute scores and write a
        for (int i = lo; i < hi; ++i) {
            int s_ = epair[i].y;
            ushort2 u = *(const ushort2*)(el_bf + (size_t)s_ * HD + l2);
            float evx = bf2f(u.x), evy = bf2f(u.y);
            float x0 = evx + rv.x; x0 = fmaxf(x0, NEG * x0);
            float x1 = evy + rv.y; x1 = fmaxf(x1, NEG * x1);
            float p = x0 * a0 + x1 * a1;
            p += __shfl_xor(p, 1, 16);
            p += __shfl_xor(p, 2, 16);
            p += __shfl_xor(p, 4, 16);
            p += __shfl_xor(p, 8, 16);
            if ((lane & 15) == 0) {
                int e = epair[i].x;
                out_a[(size_t)e * NH + hh] = __expf(p - m) * inv;
            }
        }
    }
}

extern "C" void kernel_launch(void* const* d_in, const int* in_sizes, int n_in,
                              void* d_out, int out_size, void* d_ws, size_t ws_size,
                              hipStream_t stream) {
    const float* h    = (const float*)d_in[0];
    const int*   src  = (const int*)d_in[1];
    const int*   dst  = (const int*)d_in[2];
    const float* Wsrc = (const float*)d_in[3];
    const float* bsrc = (const float*)d_in[4];
    const float* Wdst = (const float*)d_in[5];
    const float* bdst = (const float*)d_in[6];
    const float* attn = (const float*)d_in[7];

    float* out_feat = (float*)d_out;                       // N*128
    float* out_a    = out_feat + (size_t)NNODES * HD;      // E*4

    // workspace layout (16B-aligned chunks)
    float*  er       = (float*)d_ws;                         // N*128 f32
    ushort* Wt       = (ushort*)(er + (size_t)NNODES * HD);  // 256*256 bf16
    ushort* el_bf    = Wt + 2 * HD * INDIM;                  // N*128 bf16
    int*    cnt_work = (int*)(el_bf + (size_t)NNODES * HD);  // N
    int2*   epair    = (int2*)(cnt_work + NNODES);           // E  {eidx, esrc}
    int*    rowptr   = (int*)(epair + NEDGES);               // N+1
    int*    partials = rowptr + NNODES + 1;                  // SCAN_B

    hipMemsetAsync(cnt_work, 0, NNODES * sizeof(int), stream);

    // fusedA: dst histogram (8/thread) | W convert+transpose (independent)
    fusedA_kernel<<<HIST_BLKS + CONVW_BLKS, 256, 0, stream>>>(
        dst, cnt_work, Wsrc, Wdst, Wt);

    // CSR prefix-sum chain
    scan_partial_kernel<<<SCAN_B, 256, 0, stream>>>(cnt_work, partials);
    scan_offsets_kernel<<<1, 256, 0, stream>>>(partials, rowptr);
    scan_final_kernel<<<SCAN_B, 256, 0, stream>>>(cnt_work, partials, rowptr);

    // fusedB: MFMA GEMM 128x256 (el+er, f32 A direct) | CSR scatter (8/thread)
    fusedB_kernel<<<GEMM_BLKS + SCAT_BLKS, 256, 0, stream>>>(
        h, Wt, bsrc, bdst, el_bf, er, src, dst, cnt_work, epair);

    node_fused_kernel<<<(NNODES + 3) / 4, 256, 0, stream>>>(
        el_bf, er, rowptr, epair, attn, out_feat, out_a);
}